// Round 1
// baseline (437.065 us; speedup 1.0000x reference)
//
#include <hip/hip_runtime.h>
#include <cstdint>
#include <cstddef>

// ---------- types ----------
typedef __attribute__((ext_vector_type(8))) short short8;   // 8 x bf16 (4 VGPR)
typedef __attribute__((ext_vector_type(4))) float f32x4;

__device__ __forceinline__ unsigned short f2bf(float x) {
    unsigned u = __float_as_uint(x);
    u += 0x7FFFu + ((u >> 16) & 1u);        // RNE
    return (unsigned short)(u >> 16);
}
__device__ __forceinline__ float bf2f(unsigned short h) {
    return __uint_as_float(((unsigned)h) << 16);
}

// ---------- kernel 1: f32 -> bf16 hidden ----------
__global__ void convert_hidden(const float* __restrict__ in, unsigned short* __restrict__ out) {
    int i = blockIdx.x * 256 + threadIdx.x;           // 262144 float4 total
    float4 v = *(const float4*)(in + (size_t)i * 4);
    unsigned long long p = (unsigned long long)f2bf(v.x)
                         | ((unsigned long long)f2bf(v.y) << 16)
                         | ((unsigned long long)f2bf(v.z) << 32)
                         | ((unsigned long long)f2bf(v.w) << 48);
    *(unsigned long long*)(out + (size_t)i * 4) = p;
}

// ---------- kernel 2: proj_i = hidden @ P_i^T  (bf16 out, proj3 zero-padded to 64) ----------
__global__ __launch_bounds__(384)
void proj_kernel(const float* __restrict__ hidden,
                 const float* __restrict__ P1, const float* __restrict__ P2,
                 const float* __restrict__ P3,
                 unsigned short* __restrict__ proj1, unsigned short* __restrict__ proj2,
                 unsigned short* __restrict__ proj3) {
    __shared__ __align__(16) float h[8][1024];
    const int t0 = blockIdx.x * 8;
    const int tid = threadIdx.x;
    for (int f = tid; f < 2048; f += 384) {
        int tok = f >> 8, pos = (f & 255) * 4;
        *(float4*)&h[tok][pos] = *(const float4*)(hidden + (size_t)(t0 + tok) * 1024 + pos);
    }
    __syncthreads();
    const int n = tid;
    const float* Prow;
    unsigned short* outp;
    int stride;
    if (n < 256)      { Prow = P1 + (size_t)n * 1024;        outp = proj1 + n;        stride = 256; }
    else if (n < 320) { Prow = P2 + (size_t)(n - 256) * 1024; outp = proj2 + (n - 256); stride = 64; }
    else if (n < 336) { Prow = P3 + (size_t)(n - 320) * 1024; outp = proj3 + (n - 320); stride = 64; }
    else {  // zero-pad proj3 columns 16..63
        int idx = n - 320;
        for (int tok = 0; tok < 8; ++tok) proj3[(size_t)(t0 + tok) * 64 + idx] = 0;
        return;
    }
    float acc[8] = {0.f,0.f,0.f,0.f,0.f,0.f,0.f,0.f};
    for (int k = 0; k < 1024; k += 4) {
        float4 p = *(const float4*)(Prow + k);
#pragma unroll
        for (int tok = 0; tok < 8; ++tok)
            acc[tok] += p.x * h[tok][k] + p.y * h[tok][k+1] + p.z * h[tok][k+2] + p.w * h[tok][k+3];
    }
    for (int tok = 0; tok < 8; ++tok)
        outp[(size_t)(t0 + tok) * stride] = f2bf(acc[tok]);
}

// ---------- kernel 3: tiled bf16 MFMA GEMM with fused per-row (max, sumexp) partials ----------
// C[m, n0+j] = sum_k A[m,k] * B[n,k] + bias[n];  per (token, n-tile) writes (M, S) partial.
// B is f32 [N][K] (B1 rows [0,Nsplit), B2 rows [Nsplit,N)), converted to bf16 in staging.
__global__ __launch_bounds__(256)
void gemm_lse(const unsigned short* __restrict__ A, int KP, int K, int KTILES,
              const float* __restrict__ B1, int Nsplit,
              const float* __restrict__ B2, int N,
              const float* __restrict__ bias1, const float* __restrict__ bias2,
              float* __restrict__ pM, float* __restrict__ pS, int ntiles) {
    __shared__ char lds[32768];
    char* As = lds;
    char* Bs = lds + 16384;
    const int tid  = threadIdx.x;
    const int lane = tid & 63;
    const int wid  = tid >> 6;
    const int wm = wid >> 1, wn = wid & 1;          // 2x2 waves, each 64x64
    const int nt = blockIdx.x, mt = blockIdx.y;
    const int n0 = nt * 128, m0 = mt * 128;

    f32x4 acc[4][4];
    const f32x4 zero = {0.f, 0.f, 0.f, 0.f};
#pragma unroll
    for (int i = 0; i < 4; ++i)
#pragma unroll
        for (int j = 0; j < 4; ++j) acc[i][j] = zero;

    for (int kt = 0; kt < KTILES; ++kt) {
        // ---- stage A tile [128][64] bf16 (pre-padded in ws, no guards) ----
#pragma unroll
        for (int it = 0; it < 4; ++it) {
            int c = tid + it * 256;
            int row = c >> 3, kc = (c & 7) << 3;
            int4 v = *(const int4*)(A + (size_t)(m0 + row) * KP + kt * 64 + kc);
            int off = (row * 128 + kc * 2) ^ ((row & 7) << 4);
            *(int4*)(As + off) = v;
        }
        // ---- stage B tile [128][64] with f32->bf16 conversion, guarded ----
#pragma unroll
        for (int it = 0; it < 4; ++it) {
            int c = tid + it * 256;
            int row = c >> 3, kc = (c & 7) << 3;
            int n = n0 + row;
            int kg = kt * 64 + kc;
            float v[8] = {0.f,0.f,0.f,0.f,0.f,0.f,0.f,0.f};
            const float* rp = nullptr;
            if (n < Nsplit)      rp = B1 + (size_t)n * K;
            else if (n < N)      rp = B2 + (size_t)(n - Nsplit) * K;
            if (rp != nullptr && kg + 8 <= K) {
                float4 u0 = *(const float4*)(rp + kg);
                float4 u1 = *(const float4*)(rp + kg + 4);
                v[0]=u0.x; v[1]=u0.y; v[2]=u0.z; v[3]=u0.w;
                v[4]=u1.x; v[5]=u1.y; v[6]=u1.z; v[7]=u1.w;
            }
            unsigned short hh[8];
#pragma unroll
            for (int j = 0; j < 8; ++j) hh[j] = f2bf(v[j]);
            int off = (row * 128 + kc * 2) ^ ((row & 7) << 4);
            *(int4*)(Bs + off) = *(const int4*)hh;
        }
        __syncthreads();
        // ---- compute: 2 k-slices x 4x4 fragments ----
#pragma unroll
        for (int kk = 0; kk < 2; ++kk) {
            const int kbyte = (kk * 32 + ((lane >> 4) << 3)) * 2;
            short8 a[4], b[4];
#pragma unroll
            for (int mi = 0; mi < 4; ++mi) {
                int row = wm * 64 + mi * 16 + (lane & 15);
                int off = (row * 128 + kbyte) ^ ((row & 7) << 4);
                a[mi] = *(const short8*)(As + off);
            }
#pragma unroll
            for (int ni = 0; ni < 4; ++ni) {
                int row = wn * 64 + ni * 16 + (lane & 15);
                int off = (row * 128 + kbyte) ^ ((row & 7) << 4);
                b[ni] = *(const short8*)(Bs + off);
            }
#pragma unroll
            for (int mi = 0; mi < 4; ++mi)
#pragma unroll
                for (int ni = 0; ni < 4; ++ni)
                    acc[mi][ni] = __builtin_amdgcn_mfma_f32_16x16x32_bf16(a[mi], b[ni], acc[mi][ni], 0, 0, 0);
        }
        __syncthreads();
    }

    // ---- epilogue: bias + per-row max & sumexp over this 128-col tile ----
    const int cl = lane & 15;
    float bv[4];
    bool  val[4];
#pragma unroll
    for (int ni = 0; ni < 4; ++ni) {
        int col = n0 + wn * 64 + ni * 16 + cl;
        val[ni] = (col < N);
        float b = 0.f;
        if (val[ni]) b = (col < Nsplit) ? bias1[col] : bias2[col - Nsplit];
        bv[ni] = b;
    }
    float rm[4][4], rs[4][4];
#pragma unroll
    for (int mi = 0; mi < 4; ++mi) {
#pragma unroll
        for (int r = 0; r < 4; ++r) {
            float mx = -INFINITY;
#pragma unroll
            for (int ni = 0; ni < 4; ++ni)
                if (val[ni]) mx = fmaxf(mx, acc[mi][ni][r] + bv[ni]);
#pragma unroll
            for (int msk = 1; msk < 16; msk <<= 1)
                mx = fmaxf(mx, __shfl_xor(mx, msk, 64));
            float sm = 0.f;
#pragma unroll
            for (int ni = 0; ni < 4; ++ni)
                if (val[ni]) sm += __expf(acc[mi][ni][r] + bv[ni] - mx);
#pragma unroll
            for (int msk = 1; msk < 16; msk <<= 1)
                sm += __shfl_xor(sm, msk, 64);
            rm[mi][r] = mx; rs[mi][r] = sm;
        }
    }
    // cross-wave (wn) combine via LDS (tile reads are all drained past the loop's last barrier)
    float* red = (float*)lds;   // [2][128][2]
    if (cl == 0) {
#pragma unroll
        for (int mi = 0; mi < 4; ++mi)
#pragma unroll
            for (int r = 0; r < 4; ++r) {
                int row = wm * 64 + mi * 16 + ((lane >> 4) << 2) + r;
                red[(wn * 128 + row) * 2 + 0] = rm[mi][r];
                red[(wn * 128 + row) * 2 + 1] = rs[mi][r];
            }
    }
    __syncthreads();
    if (tid < 128) {
        float m0v = red[(0 * 128 + tid) * 2 + 0];
        float s0v = red[(0 * 128 + tid) * 2 + 1];
        float m1v = red[(1 * 128 + tid) * 2 + 0];
        float s1v = red[(1 * 128 + tid) * 2 + 1];
        float M = fmaxf(m0v, m1v);
        float S = 0.f;
        if (s0v > 0.f) S += s0v * __expf(m0v - M);
        if (s1v > 0.f) S += s1v * __expf(m1v - M);
        size_t idx = (size_t)(m0 + tid) * ntiles + nt;
        pM[idx] = M;
        pS[idx] = S;
    }
}

// ---------- kernel 4: combine per-tile partials -> logsumexp per token ----------
__global__ void reduce_lse(const float* __restrict__ pM, const float* __restrict__ pS,
                           int ntiles, float* __restrict__ lse) {
    const int t = blockIdx.x;
    const int lane = threadIdx.x;
    float m = -INFINITY, s = 0.f;
    for (int i = lane; i < ntiles; i += 64) {
        float mi = pM[(size_t)t * ntiles + i];
        float si = pS[(size_t)t * ntiles + i];
        if (mi > m) { s = s * __expf(m - mi) + si; m = mi; }
        else        { s += si * __expf(mi - m); }
    }
#pragma unroll
    for (int msk = 1; msk < 64; msk <<= 1) {
        float om = __shfl_xor(m, msk, 64);
        float os = __shfl_xor(s, msk, 64);
        if (om > m) { s = s * __expf(m - om) + os; m = om; }
        else        { s += os * __expf(om - m); }
    }
    if (lane == 0) lse[t] = m + logf(s);
}

// ---------- kernel 5: gather needed logits + assemble output ----------
__global__ void finalize(const float* __restrict__ hidden, const int* __restrict__ target,
                         const float* __restrict__ W_head, const float* __restrict__ b_head,
                         const float* __restrict__ W_clu, const float* __restrict__ b_clu,
                         const float* __restrict__ W1, const float* __restrict__ b1,
                         const float* __restrict__ W2, const float* __restrict__ b2,
                         const float* __restrict__ W3, const float* __restrict__ b3,
                         const unsigned short* __restrict__ proj1,
                         const unsigned short* __restrict__ proj2,
                         const unsigned short* __restrict__ proj3,
                         const float* __restrict__ lse,   // [4][1024]
                         float* __restrict__ out) {
    const int t = blockIdx.x;
    const int lane = threadIdx.x;
    const int tgt = target[t];
    const int cid = (tgt >= 20000) + (tgt >= 40000) + (tgt >= 200000);
    // head gather column: target for cluster 0, else col 20003 - cid (torch's [:, -i])
    const int j = (cid == 0) ? tgt : (20003 - cid);
    const float* wr = (j < 20000) ? (W_head + (size_t)j * 1024)
                                  : (W_clu + (size_t)(j - 20000) * 1024);
    float acc = 0.f;
#pragma unroll
    for (int i = 0; i < 4; ++i) {
        int k4 = lane + i * 64;
        float4 h = *(const float4*)(hidden + (size_t)t * 1024 + k4 * 4);
        float4 w = *(const float4*)(wr + k4 * 4);
        acc += h.x * w.x + h.y * w.y + h.z * w.z + h.w * w.w;
    }
#pragma unroll
    for (int msk = 1; msk < 64; msk <<= 1) acc += __shfl_xor(acc, msk, 64);
    float bj = (j < 20000) ? b_head[j] : b_clu[j - 20000];
    float res = (acc + bj) - lse[t];
    if (cid > 0) {
        const int starts[4] = {0, 20000, 40000, 200000};
        const int dims[4]   = {0, 256, 64, 16};
        const float* Wt = (cid == 1) ? W1 : (cid == 2) ? W2 : W3;
        const float* bt = (cid == 1) ? b1 : (cid == 2) ? b2 : b3;
        const unsigned short* pr = (cid == 1) ? proj1 + (size_t)t * 256
                                 : (cid == 2) ? proj2 + (size_t)t * 64
                                              : proj3 + (size_t)t * 64;
        int ti = tgt - starts[cid];
        int d  = dims[cid];
        const float* wt = Wt + (size_t)ti * d;
        float a2 = 0.f;
        for (int k = lane; k < d; k += 64) a2 += bf2f(pr[k]) * wt[k];
#pragma unroll
        for (int msk = 1; msk < 64; msk <<= 1) a2 += __shfl_xor(a2, msk, 64);
        res += (a2 + bt[ti]) - lse[cid * 1024 + t];
    }
    if (lane == 0) out[t] = -res;
}

// ---------- launch ----------
extern "C" void kernel_launch(void* const* d_in, const int* in_sizes, int n_in,
                              void* d_out, int out_size, void* d_ws, size_t ws_size,
                              hipStream_t stream) {
    const float* hidden = (const float*)d_in[0];
    const int*   target = (const int*)d_in[1];
    const float* W_head = (const float*)d_in[2];
    const float* b_head = (const float*)d_in[3];
    const float* W_clu  = (const float*)d_in[4];
    const float* b_clu  = (const float*)d_in[5];
    const float* P1 = (const float*)d_in[6];
    const float* W1 = (const float*)d_in[7];
    const float* b1 = (const float*)d_in[8];
    const float* P2 = (const float*)d_in[9];
    const float* W2 = (const float*)d_in[10];
    const float* b2 = (const float*)d_in[11];
    const float* P3 = (const float*)d_in[12];
    const float* W3 = (const float*)d_in[13];
    const float* b3 = (const float*)d_in[14];
    float* out = (float*)d_out;

    // workspace carve-up (~20 MB total)
    char* ws = (char*)d_ws;
    size_t off = 0;
    auto alloc = [&](size_t bytes) -> char* {
        char* p = ws + off;
        off += (bytes + 255) & ~(size_t)255;
        return p;
    };
    const int NT_H = 157;   // ceil(20003/128)
    const int NT_1 = 157;   // ceil(20000/128)
    const int NT_2 = 1250;  // 160000/128
    const int NT_3 = 530;   // ceil(67735/128)

    unsigned short* hbf   = (unsigned short*)alloc((size_t)1024 * 1024 * 2);
    unsigned short* proj1 = (unsigned short*)alloc((size_t)1024 * 256 * 2);
    unsigned short* proj2 = (unsigned short*)alloc((size_t)1024 * 64 * 2);
    unsigned short* proj3 = (unsigned short*)alloc((size_t)1024 * 64 * 2);
    float* pMh = (float*)alloc((size_t)1024 * NT_H * 4);
    float* pSh = (float*)alloc((size_t)1024 * NT_H * 4);
    float* pM1 = (float*)alloc((size_t)1024 * NT_1 * 4);
    float* pS1 = (float*)alloc((size_t)1024 * NT_1 * 4);
    float* pM2 = (float*)alloc((size_t)1024 * NT_2 * 4);
    float* pS2 = (float*)alloc((size_t)1024 * NT_2 * 4);
    float* pM3 = (float*)alloc((size_t)1024 * NT_3 * 4);
    float* pS3 = (float*)alloc((size_t)1024 * NT_3 * 4);
    float* lse = (float*)alloc((size_t)4 * 1024 * 4);

    convert_hidden<<<1024, 256, 0, stream>>>(hidden, hbf);
    proj_kernel<<<128, 384, 0, stream>>>(hidden, P1, P2, P3, proj1, proj2, proj3);

    // head: B = [W_head(20000); W_clusters(3)], K=1024
    gemm_lse<<<dim3(NT_H, 8), 256, 0, stream>>>(hbf, 1024, 1024, 16,
                                                W_head, 20000, W_clu, 20003,
                                                b_head, b_clu, pMh, pSh, NT_H);
    // tail 1: K=256
    gemm_lse<<<dim3(NT_1, 8), 256, 0, stream>>>(proj1, 256, 256, 4,
                                                W1, 20000, nullptr, 20000,
                                                b1, nullptr, pM1, pS1, NT_1);
    // tail 2: K=64
    gemm_lse<<<dim3(NT_2, 8), 256, 0, stream>>>(proj2, 64, 64, 1,
                                                W2, 160000, nullptr, 160000,
                                                b2, nullptr, pM2, pS2, NT_2);
    // tail 3: K=16 (A padded to 64)
    gemm_lse<<<dim3(NT_3, 8), 256, 0, stream>>>(proj3, 64, 16, 1,
                                                W3, 67735, nullptr, 67735,
                                                b3, nullptr, pM3, pS3, NT_3);

    reduce_lse<<<1024, 64, 0, stream>>>(pMh, pSh, NT_H, lse + 0);
    reduce_lse<<<1024, 64, 0, stream>>>(pM1, pS1, NT_1, lse + 1024);
    reduce_lse<<<1024, 64, 0, stream>>>(pM2, pS2, NT_2, lse + 2048);
    reduce_lse<<<1024, 64, 0, stream>>>(pM3, pS3, NT_3, lse + 3072);

    finalize<<<1024, 64, 0, stream>>>(hidden, target,
                                      W_head, b_head, W_clu, b_clu,
                                      W1, b1, W2, b2, W3, b3,
                                      proj1, proj2, proj3, lse, out);
}